// Round 1
// baseline (424.528 us; speedup 1.0000x reference)
//
#include <hip/hip_runtime.h>
#include <math.h>

// MoE top-2-of-8: B=1024, I=512, H=2048, O=512, E=8, K=2. All fp32.
// Routed computation: only 2 of 8 experts per token -> 8.6 GFLOP vs 34.4 dense.

#define B_TOK 1024
#define I_DIM 512
#define H_DIM 2048
#define O_DIM 512
#define E_NUM 8

// workspace byte offsets (all 16B-aligned where vector-accessed)
#define WS_COUNTS   0            // 8 ints
#define WS_OFFSETS  32           // 8 ints
#define WS_TOK_E    64           // [1024][2] int
#define WS_TOK_W    8256         // [1024][2] float
#define WS_SLOT_TOK 16448        // [2048] int
#define WS_SLOT_WT  24640        // [2048] float
#define WS_TOK_SLOT 32832        // [1024][2] int
#define WS_H        65536        // [2048][2048] float = 16 MB
#define WS_Y        (65536 + 2048*2048*4)   // [2048][512] float = 4 MB

__global__ __launch_bounds__(64) void zero_counts_kernel(int* __restrict__ p) {
    p[threadIdx.x & 15] = 0;   // zeros counts[8] + offsets[8]
}

// One wave per token: logits = x @ Wg + bg, top-2 by logits, renormalized
// top-2 softmax weights. Wg is [I=512, E=8] row-major: each row = 8 floats.
__global__ __launch_bounds__(256) void gating_kernel(
    const float* __restrict__ x, const float* __restrict__ Wg,
    const float* __restrict__ bg,
    int* __restrict__ counts, int* __restrict__ tok_e, float* __restrict__ tok_w)
{
    const int lane = threadIdx.x & 63;
    const int t = blockIdx.x * 4 + (threadIdx.x >> 6);
    const float* xr = x + (size_t)t * I_DIM;
    float acc[8];
#pragma unroll
    for (int e = 0; e < 8; ++e) acc[e] = 0.f;
    for (int i = lane; i < I_DIM; i += 64) {
        float xv = xr[i];
        const float4* wr = (const float4*)(Wg + (size_t)i * 8);
        float4 wa = wr[0], wb = wr[1];
        acc[0] = fmaf(xv, wa.x, acc[0]);
        acc[1] = fmaf(xv, wa.y, acc[1]);
        acc[2] = fmaf(xv, wa.z, acc[2]);
        acc[3] = fmaf(xv, wa.w, acc[3]);
        acc[4] = fmaf(xv, wb.x, acc[4]);
        acc[5] = fmaf(xv, wb.y, acc[5]);
        acc[6] = fmaf(xv, wb.z, acc[6]);
        acc[7] = fmaf(xv, wb.w, acc[7]);
    }
#pragma unroll
    for (int off = 32; off > 0; off >>= 1) {
#pragma unroll
        for (int e = 0; e < 8; ++e)
            acc[e] += __shfl_xor(acc[e], off, 64);
    }
    if (lane == 0) {
        float l[8];
#pragma unroll
        for (int e = 0; e < 8; ++e) l[e] = acc[e] + bg[e];
        int e0 = 0;
        for (int e = 1; e < 8; ++e) if (l[e] > l[e0]) e0 = e;       // lowest-index tie-break
        int e1 = (e0 == 0) ? 1 : 0;
        for (int e = 0; e < 8; ++e) {
            if (e == e0) continue;
            if (l[e] > l[e1]) e1 = e;
        }
        // renormalized top-2 softmax: w0 = p0/(p0+p1) = 1/(1+exp(l1-l0))
        float w0 = 1.f / (1.f + expf(l[e1] - l[e0]));
        float w1 = 1.f - w0;
        tok_e[t * 2]     = e0;
        tok_e[t * 2 + 1] = e1;
        tok_w[t * 2]     = w0;
        tok_w[t * 2 + 1] = w1;
        atomicAdd(&counts[e0], 1);
        atomicAdd(&counts[e1], 1);
    }
}

// Single block: exclusive prefix over 8 counts, then scatter tokens into
// compact per-expert slot lists. Total slots = 2*B = 2048 exactly.
__global__ __launch_bounds__(1024) void scatter_kernel(
    const int* __restrict__ counts, const int* __restrict__ tok_e,
    const float* __restrict__ tok_w,
    int* __restrict__ offsets, int* __restrict__ slot_token,
    float* __restrict__ slot_wt, int* __restrict__ tok_slot)
{
    __shared__ int soff[8];
    __shared__ int scur[8];
    const int tid = threadIdx.x;
    if (tid == 0) {
        int run = 0;
        for (int e = 0; e < 8; ++e) { soff[e] = run; run += counts[e]; }
    }
    if (tid < 8) scur[tid] = 0;
    __syncthreads();
    if (tid < 8) offsets[tid] = soff[tid];
    const int t = tid;
#pragma unroll
    for (int k = 0; k < 2; ++k) {
        int e = tok_e[t * 2 + k];
        int pos = atomicAdd(&scur[e], 1);
        int slot = soff[e] + pos;
        slot_token[slot] = t;
        slot_wt[slot] = tok_w[t * 2 + k];
        tok_slot[t * 2 + k] = slot;
    }
}

// FC1: h[slot] = relu(x[token] @ W1[e] + b1[e]).  M=count[e] (gathered rows),
// K=512, N=2048.  64x64 tile, 256 threads, 4x4 micro-tile, BK=16.
__global__ __launch_bounds__(256) void expert_fc1(
    const float* __restrict__ x, const float* __restrict__ W1,
    const float* __restrict__ b1,
    const int* __restrict__ counts, const int* __restrict__ offsets,
    const int* __restrict__ slot_token, float* __restrict__ h)
{
    const int e  = blockIdx.z;
    const int Me = counts[e];
    const int m0 = blockIdx.y * 64;
    if (m0 >= Me) return;
    const int n0 = blockIdx.x * 64;
    const int off = offsets[e];
    const float* W = W1 + (size_t)e * I_DIM * H_DIM;

    __shared__ float As[16][68];   // +4 pad: aligned b128 reads, 2-way (free) write aliasing
    __shared__ float Bs[16][64];
    __shared__ int toks[64];

    const int tid = threadIdx.x;
    if (tid < 64) {
        int m = m0 + tid;
        if (m >= Me) m = Me - 1;   // clamp: loads valid, stores guarded
        toks[tid] = slot_token[off + m];
    }
    __syncthreads();

    const int tr = tid >> 4, tc = tid & 15;
    const int ar = tid >> 2, ac = (tid & 3) * 4;
    const int bcol = tid & 63, brow0 = tid >> 6;
    const float* arow = x + (size_t)toks[ar] * I_DIM + ac;

    float acc[4][4] = {{0.f, 0.f, 0.f, 0.f}};

    for (int k0 = 0; k0 < I_DIM; k0 += 16) {
        float4 av = *(const float4*)(arow + k0);
        As[ac + 0][ar] = av.x;
        As[ac + 1][ar] = av.y;
        As[ac + 2][ar] = av.z;
        As[ac + 3][ar] = av.w;
#pragma unroll
        for (int p = 0; p < 4; ++p) {
            int row = p * 4 + brow0;
            Bs[row][bcol] = W[(size_t)(k0 + row) * H_DIM + n0 + bcol];
        }
        __syncthreads();
#pragma unroll
        for (int kk = 0; kk < 16; ++kk) {
            float4 a4 = *(const float4*)&As[kk][tr * 4];
            float4 b4 = *(const float4*)&Bs[kk][tc * 4];
            float a[4] = {a4.x, a4.y, a4.z, a4.w};
            float b[4] = {b4.x, b4.y, b4.z, b4.w};
#pragma unroll
            for (int i = 0; i < 4; ++i)
#pragma unroll
                for (int j = 0; j < 4; ++j)
                    acc[i][j] = fmaf(a[i], b[j], acc[i][j]);
        }
        __syncthreads();
    }

    const float4 bias = *(const float4*)(b1 + (size_t)e * H_DIM + n0 + tc * 4);
#pragma unroll
    for (int i = 0; i < 4; ++i) {
        int m = m0 + tr * 4 + i;
        if (m < Me) {
            float4 o;
            o.x = fmaxf(acc[i][0] + bias.x, 0.f);
            o.y = fmaxf(acc[i][1] + bias.y, 0.f);
            o.z = fmaxf(acc[i][2] + bias.z, 0.f);
            o.w = fmaxf(acc[i][3] + bias.w, 0.f);
            *(float4*)(h + (size_t)(off + m) * H_DIM + n0 + tc * 4) = o;
        }
    }
}

// FC2: y[slot] = gate_w[slot] * (h[slot] @ W2[e] + b2[e]).  K=2048, N=512.
__global__ __launch_bounds__(256) void expert_fc2(
    const float* __restrict__ h, const float* __restrict__ W2,
    const float* __restrict__ b2,
    const int* __restrict__ counts, const int* __restrict__ offsets,
    const float* __restrict__ slot_wt, float* __restrict__ y)
{
    const int e  = blockIdx.z;
    const int Me = counts[e];
    const int m0 = blockIdx.y * 64;
    if (m0 >= Me) return;
    const int n0 = blockIdx.x * 64;
    const int off = offsets[e];
    const float* W = W2 + (size_t)e * H_DIM * O_DIM;

    __shared__ float As[16][68];
    __shared__ float Bs[16][64];

    const int tid = threadIdx.x;
    const int tr = tid >> 4, tc = tid & 15;
    const int ar = tid >> 2, ac = (tid & 3) * 4;
    const int bcol = tid & 63, brow0 = tid >> 6;
    int ma = m0 + ar;
    if (ma >= Me) ma = Me - 1;
    const float* arow = h + (size_t)(off + ma) * H_DIM + ac;

    float acc[4][4] = {{0.f, 0.f, 0.f, 0.f}};

    for (int k0 = 0; k0 < H_DIM; k0 += 16) {
        float4 av = *(const float4*)(arow + k0);
        As[ac + 0][ar] = av.x;
        As[ac + 1][ar] = av.y;
        As[ac + 2][ar] = av.z;
        As[ac + 3][ar] = av.w;
#pragma unroll
        for (int p = 0; p < 4; ++p) {
            int row = p * 4 + brow0;
            Bs[row][bcol] = W[(size_t)(k0 + row) * O_DIM + n0 + bcol];
        }
        __syncthreads();
#pragma unroll
        for (int kk = 0; kk < 16; ++kk) {
            float4 a4 = *(const float4*)&As[kk][tr * 4];
            float4 b4 = *(const float4*)&Bs[kk][tc * 4];
            float a[4] = {a4.x, a4.y, a4.z, a4.w};
            float b[4] = {b4.x, b4.y, b4.z, b4.w};
#pragma unroll
            for (int i = 0; i < 4; ++i)
#pragma unroll
                for (int j = 0; j < 4; ++j)
                    acc[i][j] = fmaf(a[i], b[j], acc[i][j]);
        }
        __syncthreads();
    }

    const float4 bias = *(const float4*)(b2 + (size_t)e * O_DIM + n0 + tc * 4);
#pragma unroll
    for (int i = 0; i < 4; ++i) {
        int m = m0 + tr * 4 + i;
        if (m < Me) {
            int slot = off + m;
            float w = slot_wt[slot];
            float4 o;
            o.x = w * (acc[i][0] + bias.x);
            o.y = w * (acc[i][1] + bias.y);
            o.z = w * (acc[i][2] + bias.z);
            o.w = w * (acc[i][3] + bias.w);
            *(float4*)(y + (size_t)slot * O_DIM + n0 + tc * 4) = o;
        }
    }
}

// out[t] = y[slot0(t)] + y[slot1(t)]  (gate weights + biases already folded in)
__global__ __launch_bounds__(256) void combine_kernel(
    const float* __restrict__ y, const int* __restrict__ tok_slot,
    float* __restrict__ out)
{
    const int idx = blockIdx.x * 256 + threadIdx.x;   // over B*O/4
    const int t = idx >> 7;                           // O/4 = 128 float4 per row
    const int c = (idx & 127) * 4;
    const int s0 = tok_slot[t * 2];
    const int s1 = tok_slot[t * 2 + 1];
    const float4 v0 = *(const float4*)(y + (size_t)s0 * O_DIM + c);
    const float4 v1 = *(const float4*)(y + (size_t)s1 * O_DIM + c);
    float4 o;
    o.x = v0.x + v1.x;
    o.y = v0.y + v1.y;
    o.z = v0.z + v1.z;
    o.w = v0.w + v1.w;
    *(float4*)(out + (size_t)t * O_DIM + c) = o;
}

extern "C" void kernel_launch(void* const* d_in, const int* in_sizes, int n_in,
                              void* d_out, int out_size, void* d_ws, size_t ws_size,
                              hipStream_t stream)
{
    const float* x  = (const float*)d_in[0];
    const float* Wg = (const float*)d_in[1];
    const float* bg = (const float*)d_in[2];
    const float* W1 = (const float*)d_in[3];
    const float* b1 = (const float*)d_in[4];
    const float* W2 = (const float*)d_in[5];
    const float* b2 = (const float*)d_in[6];
    float* out = (float*)d_out;
    char* ws = (char*)d_ws;

    int*   counts   = (int*)(ws + WS_COUNTS);
    int*   offsets  = (int*)(ws + WS_OFFSETS);
    int*   tok_e    = (int*)(ws + WS_TOK_E);
    float* tok_w    = (float*)(ws + WS_TOK_W);
    int*   slot_tok = (int*)(ws + WS_SLOT_TOK);
    float* slot_wt  = (float*)(ws + WS_SLOT_WT);
    int*   tok_slot = (int*)(ws + WS_TOK_SLOT);
    float* h        = (float*)(ws + WS_H);
    float* y        = (float*)(ws + WS_Y);

    zero_counts_kernel<<<1, 64, 0, stream>>>(counts);
    gating_kernel<<<B_TOK / 4, 256, 0, stream>>>(x, Wg, bg, counts, tok_e, tok_w);
    scatter_kernel<<<1, B_TOK, 0, stream>>>(counts, tok_e, tok_w, offsets,
                                            slot_tok, slot_wt, tok_slot);
    expert_fc1<<<dim3(H_DIM / 64, B_TOK / 64, E_NUM), 256, 0, stream>>>(
        x, W1, b1, counts, offsets, slot_tok, h);
    expert_fc2<<<dim3(O_DIM / 64, B_TOK / 64, E_NUM), 256, 0, stream>>>(
        h, W2, b2, counts, offsets, slot_wt, y);
    combine_kernel<<<(B_TOK * O_DIM / 4) / 256, 256, 0, stream>>>(y, tok_slot, out);
}

// Round 2
// 203.648 us; speedup vs baseline: 2.0846x; 2.0846x over previous
//
#include <hip/hip_runtime.h>
#include <math.h>

// MoE top-2-of-8: B=1024, I=512, H=2048, O=512, E=8, K=2.
// R2: bf16 MFMA GEMMs (fp32 accumulate), routed computation (8.6 GFLOP).
//   fc1: h[slot] = relu(x[tok] @ W1[e] + b1)   M~2048, N=2048, K=512
//   fc2: out[tok] += w * (h[slot] @ W2[e] + b2)  via split-K=4 + fp32 atomicAdd
// Both GEMMs: 64x64 tile / 256 thr / 4 waves of 32x32 (2x2 mfma 16x16x32 bf16),
// BK=32, fp32->bf16 convert at LDS staging, all LDS traffic ds_*_b128.

#define B_TOK 1024
#define I_DIM 512
#define H_DIM 2048
#define O_DIM 512
#define E_NUM 8

#define WS_COUNTS   0            // 8 ints
#define WS_OFFSETS  32           // 8 ints
#define WS_TOK_E    64           // [1024][2] int
#define WS_TOK_W    8256         // [1024][2] float
#define WS_SLOT_TOK 16448        // [2048] int
#define WS_SLOT_WT  24640        // [2048] float
#define WS_H        65536        // [2048][2048] float = 16 MB

typedef __attribute__((ext_vector_type(8))) __bf16 bf16x8;
typedef __attribute__((ext_vector_type(4))) float f32x4;

#define MFMA16 __builtin_amdgcn_mfma_f32_16x16x32_bf16

// Zero out[] (poisoned 0xAA) + counts/offsets. grid 512x256 covers 1024*512 f32.
__global__ __launch_bounds__(256) void zero_kernel(float4* __restrict__ out,
                                                   int* __restrict__ cnt) {
    out[blockIdx.x * 256 + threadIdx.x] = float4{0.f, 0.f, 0.f, 0.f};
    if (blockIdx.x == 0 && threadIdx.x < 16) cnt[threadIdx.x] = 0;
}

// One wave per token: logits = x @ Wg + bg, top-2, renormalized softmax weights.
__global__ __launch_bounds__(256) void gating_kernel(
    const float* __restrict__ x, const float* __restrict__ Wg,
    const float* __restrict__ bg,
    int* __restrict__ counts, int* __restrict__ tok_e, float* __restrict__ tok_w)
{
    const int lane = threadIdx.x & 63;
    const int t = blockIdx.x * 4 + (threadIdx.x >> 6);
    const float* xr = x + (size_t)t * I_DIM;
    float acc[8];
#pragma unroll
    for (int e = 0; e < 8; ++e) acc[e] = 0.f;
    for (int i = lane; i < I_DIM; i += 64) {
        float xv = xr[i];
        const float4* wr = (const float4*)(Wg + (size_t)i * 8);
        float4 wa = wr[0], wb = wr[1];
        acc[0] = fmaf(xv, wa.x, acc[0]);
        acc[1] = fmaf(xv, wa.y, acc[1]);
        acc[2] = fmaf(xv, wa.z, acc[2]);
        acc[3] = fmaf(xv, wa.w, acc[3]);
        acc[4] = fmaf(xv, wb.x, acc[4]);
        acc[5] = fmaf(xv, wb.y, acc[5]);
        acc[6] = fmaf(xv, wb.z, acc[6]);
        acc[7] = fmaf(xv, wb.w, acc[7]);
    }
#pragma unroll
    for (int off = 32; off > 0; off >>= 1)
#pragma unroll
        for (int e = 0; e < 8; ++e)
            acc[e] += __shfl_xor(acc[e], off, 64);
    if (lane == 0) {
        float l[8];
#pragma unroll
        for (int e = 0; e < 8; ++e) l[e] = acc[e] + bg[e];
        int e0 = 0;
        for (int e = 1; e < 8; ++e) if (l[e] > l[e0]) e0 = e;
        int e1 = (e0 == 0) ? 1 : 0;
        for (int e = 0; e < 8; ++e) {
            if (e == e0) continue;
            if (l[e] > l[e1]) e1 = e;
        }
        float w0 = 1.f / (1.f + expf(l[e1] - l[e0]));  // p0/(p0+p1)
        tok_e[t * 2]     = e0;
        tok_e[t * 2 + 1] = e1;
        tok_w[t * 2]     = w0;
        tok_w[t * 2 + 1] = 1.f - w0;
        atomicAdd(&counts[e0], 1);
        atomicAdd(&counts[e1], 1);
    }
}

// Single block: prefix over 8 counts, scatter into compact per-expert slot lists.
__global__ __launch_bounds__(1024) void scatter_kernel(
    const int* __restrict__ counts, const int* __restrict__ tok_e,
    const float* __restrict__ tok_w,
    int* __restrict__ offsets, int* __restrict__ slot_token,
    float* __restrict__ slot_wt)
{
    __shared__ int soff[8];
    __shared__ int scur[8];
    const int tid = threadIdx.x;
    if (tid == 0) {
        int run = 0;
        for (int e = 0; e < 8; ++e) { soff[e] = run; run += counts[e]; }
    }
    if (tid < 8) scur[tid] = 0;
    __syncthreads();
    if (tid < 8) offsets[tid] = soff[tid];
#pragma unroll
    for (int k = 0; k < 2; ++k) {
        int e = tok_e[tid * 2 + k];
        int pos = atomicAdd(&scur[e], 1);
        int slot = soff[e] + pos;
        slot_token[slot] = tid;
        slot_wt[slot] = tok_w[tid * 2 + k];
    }
}

// Unified MFMA GEMM.
// IS_FC1:  A = x [1024][512] gathered via slot_token; Out = h [2048][2048] (relu+bias)
// !IS_FC1: A = h [2048][2048] direct; Out = out [1024][512] via atomicAdd, split-K=4
template <bool IS_FC1>
__global__ __launch_bounds__(256) void moe_gemm(
    const float* __restrict__ A, const float* __restrict__ Wfull,
    const float* __restrict__ bias,
    const int* __restrict__ counts, const int* __restrict__ offsets,
    const int* __restrict__ slot_token, const float* __restrict__ slot_wt,
    float* __restrict__ Out)
{
    constexpr int N  = IS_FC1 ? H_DIM : O_DIM;   // 2048 / 512
    constexpr int K  = IS_FC1 ? I_DIM : H_DIM;   // 512 / 2048
    constexpr int ASR = IS_FC1 ? I_DIM : H_DIM;  // A row stride

    const int e  = IS_FC1 ? blockIdx.z : (blockIdx.z & 7);
    const int kc = IS_FC1 ? 0 : (int)(blockIdx.z >> 3);   // split-K chunk (fc2)
    const int Me = counts[e];
    const int m0 = blockIdx.y * 64;
    if (m0 >= Me) return;
    const int n0 = blockIdx.x * 64;
    const int off = offsets[e];
    const int k0base = kc * 512;
    const float* W = Wfull + (size_t)e * K * N;

    __shared__ __align__(16) __bf16 As[64][40];   // stride 80B: 16B-aligned rows
    __shared__ __align__(16) __bf16 Bs[64][40];   // [n][k] (transposed at staging)
    __shared__ int toks[64];

    const int tid = threadIdx.x;
    if (tid < 64) {
        int m = m0 + tid;
        if (m >= Me) m = Me - 1;          // clamp: loads valid, stores guarded
        toks[tid] = slot_token[off + m];
    }
    __syncthreads();

    // A staging: thread -> row ar (0..63), k-oct akq (0/8/16/24); 2 float4 -> 1 b128
    const int ar = tid >> 2;
    const int akq = (tid & 3) * 8;
    const float* arow;
    if (IS_FC1) {
        arow = A + (size_t)toks[ar] * ASR + akq;
    } else {
        int m = m0 + ar;
        if (m >= Me) m = Me - 1;
        arow = A + (size_t)(off + m) * ASR + k0base + akq;
    }
    // B staging: thread -> col bn (0..63), k-oct bk (0/8/16/24); 8 strided dwords -> 1 b128
    const int bn = tid & 63;
    const int bk = (tid >> 6) * 8;
    const float* wcol = W + (size_t)(k0base + bk) * N + n0 + bn;

    const int lane = tid & 63;
    const int wave = tid >> 6;
    const int wm = (wave >> 1) * 32, wn = (wave & 1) * 32;
    const int l15 = lane & 15, q = lane >> 4;

    f32x4 acc[2][2] = {};

    for (int ks = 0; ks < 16; ++ks) {     // 16 * BK32 = 512 K per (chunk)
        float4 a0 = *(const float4*)(arow + ks * 32);
        float4 a1 = *(const float4*)(arow + ks * 32 + 4);
        bf16x8 av;
        av[0] = (__bf16)a0.x; av[1] = (__bf16)a0.y;
        av[2] = (__bf16)a0.z; av[3] = (__bf16)a0.w;
        av[4] = (__bf16)a1.x; av[5] = (__bf16)a1.y;
        av[6] = (__bf16)a1.z; av[7] = (__bf16)a1.w;

        const float* wp = wcol + (size_t)ks * 32 * N;
        float b0 = wp[0];
        float b1 = wp[(size_t)N];
        float b2 = wp[(size_t)2 * N];
        float b3 = wp[(size_t)3 * N];
        float b4 = wp[(size_t)4 * N];
        float b5 = wp[(size_t)5 * N];
        float b6 = wp[(size_t)6 * N];
        float b7 = wp[(size_t)7 * N];
        bf16x8 bv;
        bv[0] = (__bf16)b0; bv[1] = (__bf16)b1;
        bv[2] = (__bf16)b2; bv[3] = (__bf16)b3;
        bv[4] = (__bf16)b4; bv[5] = (__bf16)b5;
        bv[6] = (__bf16)b6; bv[7] = (__bf16)b7;

        *(bf16x8*)&As[ar][akq] = av;
        *(bf16x8*)&Bs[bn][bk]  = bv;
        __syncthreads();

        bf16x8 af0 = *(bf16x8*)&As[wm + l15][q * 8];
        bf16x8 af1 = *(bf16x8*)&As[wm + 16 + l15][q * 8];
        bf16x8 bf0 = *(bf16x8*)&Bs[wn + l15][q * 8];
        bf16x8 bf1 = *(bf16x8*)&Bs[wn + 16 + l15][q * 8];
        acc[0][0] = MFMA16(af0, bf0, acc[0][0], 0, 0, 0);
        acc[0][1] = MFMA16(af0, bf1, acc[0][1], 0, 0, 0);
        acc[1][0] = MFMA16(af1, bf0, acc[1][0], 0, 0, 0);
        acc[1][1] = MFMA16(af1, bf1, acc[1][1], 0, 0, 0);
        __syncthreads();
    }

    // Epilogue. C/D layout (verified m89): col = lane&15, row = (lane>>4)*4 + reg.
#pragma unroll
    for (int j = 0; j < 2; ++j) {
        const int gn = n0 + wn + j * 16 + l15;
        if (IS_FC1) {
            const float bv = bias[e * H_DIM + gn];
#pragma unroll
            for (int i = 0; i < 2; ++i) {
#pragma unroll
                for (int r = 0; r < 4; ++r) {
                    int mrel = wm + i * 16 + q * 4 + r;
                    int m = m0 + mrel;
                    if (m < Me) {
                        float v = acc[i][j][r] + bv;
                        Out[(size_t)(off + m) * H_DIM + gn] = fmaxf(v, 0.f);
                    }
                }
            }
        } else {
            const float bv = (kc == 0) ? bias[e * O_DIM + gn] : 0.f;
#pragma unroll
            for (int i = 0; i < 2; ++i) {
#pragma unroll
                for (int r = 0; r < 4; ++r) {
                    int mrel = wm + i * 16 + q * 4 + r;
                    int m = m0 + mrel;
                    if (m < Me) {
                        int slot = off + m;
                        float w = slot_wt[slot];
                        int tok = toks[mrel];
                        atomicAdd(&Out[(size_t)tok * O_DIM + gn],
                                  w * (acc[i][j][r] + bv));
                    }
                }
            }
        }
    }
}

extern "C" void kernel_launch(void* const* d_in, const int* in_sizes, int n_in,
                              void* d_out, int out_size, void* d_ws, size_t ws_size,
                              hipStream_t stream)
{
    const float* x  = (const float*)d_in[0];
    const float* Wg = (const float*)d_in[1];
    const float* bg = (const float*)d_in[2];
    const float* W1 = (const float*)d_in[3];
    const float* b1 = (const float*)d_in[4];
    const float* W2 = (const float*)d_in[5];
    const float* b2 = (const float*)d_in[6];
    float* out = (float*)d_out;
    char* ws = (char*)d_ws;

    int*   counts   = (int*)(ws + WS_COUNTS);
    int*   offsets  = (int*)(ws + WS_OFFSETS);
    int*   tok_e    = (int*)(ws + WS_TOK_E);
    float* tok_w    = (float*)(ws + WS_TOK_W);
    int*   slot_tok = (int*)(ws + WS_SLOT_TOK);
    float* slot_wt  = (float*)(ws + WS_SLOT_WT);
    float* h        = (float*)(ws + WS_H);

    zero_kernel<<<512, 256, 0, stream>>>((float4*)out, counts);
    gating_kernel<<<B_TOK / 4, 256, 0, stream>>>(x, Wg, bg, counts, tok_e, tok_w);
    scatter_kernel<<<1, B_TOK, 0, stream>>>(counts, tok_e, tok_w, offsets,
                                            slot_tok, slot_wt);
    // fc1: x-gather -> h.  grid: n-tiles x m-tiles(max) x experts
    moe_gemm<true><<<dim3(H_DIM / 64, 32, E_NUM), 256, 0, stream>>>(
        x, W1, b1, counts, offsets, slot_tok, slot_wt, h);
    // fc2: h -> out (atomic), split-K=4 packed into z = e + 8*kc
    moe_gemm<false><<<dim3(O_DIM / 64, 32, E_NUM * 4), 256, 0, stream>>>(
        h, W2, b2, counts, offsets, slot_tok, slot_wt, out);
}

// Round 3
// 198.574 us; speedup vs baseline: 2.1379x; 1.0255x over previous
//
#include <hip/hip_runtime.h>
#include <math.h>

// MoE top-2-of-8: B=1024, I=512, H=2048, O=512, E=8, K=2.
// R3: prologue converts W1/W2/x to bf16 (weights transposed to [n][k]) so both
// GEMMs stage A and B with one contiguous bf16x8 load per thread per BK=32,
// plus register prefetch of the next K-step. h kept bf16. GEMM fragment math
// identical to R2 (verified).

#define B_TOK 1024
#define I_DIM 512
#define H_DIM 2048
#define O_DIM 512
#define E_NUM 8

#define WS_COUNTS   0                    // 8 ints
#define WS_OFFSETS  32                   // 8 ints
#define WS_TOK_E    64                   // [1024][2] int
#define WS_TOK_W    8256                 // [1024][2] float
#define WS_SLOT_TOK 16448                // [2048] int
#define WS_SLOT_WT  24640                // [2048] float
#define WS_XB       65536                // [1024][512] bf16 = 1 MB
#define WS_HB       (WS_XB + 1048576)    // [2048][2048] bf16 = 8 MB
#define WS_W1T      (WS_HB + 8388608)    // [8][2048][512] bf16 = 16 MB
#define WS_W2T      (WS_W1T + 16777216)  // [8][512][2048] bf16 = 16 MB
// total ~43.1 MB

typedef __attribute__((ext_vector_type(8))) __bf16 bf16x8;
typedef __attribute__((ext_vector_type(4))) __bf16 bf16x4;
typedef __attribute__((ext_vector_type(4))) float f32x4;

#define MFMA16 __builtin_amdgcn_mfma_f32_16x16x32_bf16

// Zero out (0xAA-poisoned) + counts; convert x fp32 -> bf16. 512 blocks x 256.
__global__ __launch_bounds__(256) void prep_kernel(
    const float4* __restrict__ x4, float4* __restrict__ out4,
    __bf16* __restrict__ xb, int* __restrict__ cnt)
{
    const int idx = blockIdx.x * 256 + threadIdx.x;   // 131072 float4s
    out4[idx] = float4{0.f, 0.f, 0.f, 0.f};
    float4 v = x4[idx];
    bf16x4 o;
    o[0] = (__bf16)v.x; o[1] = (__bf16)v.y;
    o[2] = (__bf16)v.z; o[3] = (__bf16)v.w;
    *(bf16x4*)(xb + (size_t)idx * 4) = o;
    if (blockIdx.x == 0 && threadIdx.x < 16) cnt[threadIdx.x] = 0;
}

// Transpose+convert per-expert weights: W[R][C] fp32 -> Wt[C][R] bf16.
// 32x32 tiles, 256 threads. id<8192: W1 (R=512,C=2048); else W2 (R=2048,C=512).
__global__ __launch_bounds__(256) void wconv_kernel(
    const float* __restrict__ W1, const float* __restrict__ W2,
    __bf16* __restrict__ W1t, __bf16* __restrict__ W2t)
{
    int id = blockIdx.x;
    const float* W;
    __bf16* Wt;
    int R, C;
    if (id < 8192) { W = W1; Wt = W1t; R = I_DIM; C = H_DIM; }
    else { id -= 8192; W = W2; Wt = W2t; R = H_DIM; C = O_DIM; }
    const int e = id >> 10;              // 1024 tiles per expert
    const int t = id & 1023;
    const int tpr = C >> 5;
    const int r0 = (t / tpr) * 32;
    const int c0 = (t % tpr) * 32;
    W  += (size_t)e * R * C;
    Wt += (size_t)e * R * C;

    __shared__ __bf16 T[32][36];
    const int tid = threadIdx.x;
    const int row = tid >> 3;            // 0..31
    const int c4  = (tid & 7) * 4;       // 0..28
    float4 v = *(const float4*)(W + (size_t)(r0 + row) * C + c0 + c4);
    T[c4 + 0][row] = (__bf16)v.x;
    T[c4 + 1][row] = (__bf16)v.y;
    T[c4 + 2][row] = (__bf16)v.z;
    T[c4 + 3][row] = (__bf16)v.w;
    __syncthreads();
    bf16x4 o;
    o[0] = T[row][c4 + 0];
    o[1] = T[row][c4 + 1];
    o[2] = T[row][c4 + 2];
    o[3] = T[row][c4 + 3];
    *(bf16x4*)(Wt + (size_t)(c0 + row) * R + r0 + c4) = o;
}

// One wave per token: logits = x @ Wg + bg, top-2, renormalized softmax weights.
__global__ __launch_bounds__(256) void gating_kernel(
    const float* __restrict__ x, const float* __restrict__ Wg,
    const float* __restrict__ bg,
    int* __restrict__ counts, int* __restrict__ tok_e, float* __restrict__ tok_w)
{
    const int lane = threadIdx.x & 63;
    const int t = blockIdx.x * 4 + (threadIdx.x >> 6);
    const float* xr = x + (size_t)t * I_DIM;
    float acc[8];
#pragma unroll
    for (int e = 0; e < 8; ++e) acc[e] = 0.f;
    for (int i = lane; i < I_DIM; i += 64) {
        float xv = xr[i];
        const float4* wr = (const float4*)(Wg + (size_t)i * 8);
        float4 wa = wr[0], wb = wr[1];
        acc[0] = fmaf(xv, wa.x, acc[0]);
        acc[1] = fmaf(xv, wa.y, acc[1]);
        acc[2] = fmaf(xv, wa.z, acc[2]);
        acc[3] = fmaf(xv, wa.w, acc[3]);
        acc[4] = fmaf(xv, wb.x, acc[4]);
        acc[5] = fmaf(xv, wb.y, acc[5]);
        acc[6] = fmaf(xv, wb.z, acc[6]);
        acc[7] = fmaf(xv, wb.w, acc[7]);
    }
#pragma unroll
    for (int off = 32; off > 0; off >>= 1)
#pragma unroll
        for (int e = 0; e < 8; ++e)
            acc[e] += __shfl_xor(acc[e], off, 64);
    if (lane == 0) {
        float l[8];
#pragma unroll
        for (int e = 0; e < 8; ++e) l[e] = acc[e] + bg[e];
        int e0 = 0;
        for (int e = 1; e < 8; ++e) if (l[e] > l[e0]) e0 = e;
        int e1 = (e0 == 0) ? 1 : 0;
        for (int e = 0; e < 8; ++e) {
            if (e == e0) continue;
            if (l[e] > l[e1]) e1 = e;
        }
        float w0 = 1.f / (1.f + expf(l[e1] - l[e0]));  // p0/(p0+p1)
        tok_e[t * 2]     = e0;
        tok_e[t * 2 + 1] = e1;
        tok_w[t * 2]     = w0;
        tok_w[t * 2 + 1] = 1.f - w0;
        atomicAdd(&counts[e0], 1);
        atomicAdd(&counts[e1], 1);
    }
}

// Single block: prefix over 8 counts, scatter into compact per-expert slot lists.
__global__ __launch_bounds__(1024) void scatter_kernel(
    const int* __restrict__ counts, const int* __restrict__ tok_e,
    const float* __restrict__ tok_w,
    int* __restrict__ offsets, int* __restrict__ slot_token,
    float* __restrict__ slot_wt)
{
    __shared__ int soff[8];
    __shared__ int scur[8];
    const int tid = threadIdx.x;
    if (tid == 0) {
        int run = 0;
        for (int e = 0; e < 8; ++e) { soff[e] = run; run += counts[e]; }
    }
    if (tid < 8) scur[tid] = 0;
    __syncthreads();
    if (tid < 8) offsets[tid] = soff[tid];
#pragma unroll
    for (int k = 0; k < 2; ++k) {
        int e = tok_e[tid * 2 + k];
        int pos = atomicAdd(&scur[e], 1);
        int slot = soff[e] + pos;
        slot_token[slot] = tid;
        slot_wt[slot] = tok_w[tid * 2 + k];
    }
}

// Unified bf16 MFMA GEMM, 64x64 tile, 256 thr, BK=32, register prefetch.
// IS_FC1:  A=xb gathered, B=W1t[e] ([n=2048][k=512]), Out=hb bf16 (relu+bias)
// !IS_FC1: A=hb direct,   B=W2t[e] ([n=512][k=2048]), Out=out f32 atomic, split-K=4
template <bool IS_FC1>
__global__ __launch_bounds__(256) void moe_gemm(
    const __bf16* __restrict__ A, const __bf16* __restrict__ Wt,
    const float* __restrict__ bias,
    const int* __restrict__ counts, const int* __restrict__ offsets,
    const int* __restrict__ slot_token, const float* __restrict__ slot_wt,
    void* __restrict__ out_)
{
    constexpr int N   = IS_FC1 ? H_DIM : O_DIM;
    constexpr int K   = IS_FC1 ? I_DIM : H_DIM;
    constexpr int ASR = IS_FC1 ? I_DIM : H_DIM;

    const int e  = IS_FC1 ? blockIdx.z : (blockIdx.z & 7);
    const int kc = IS_FC1 ? 0 : (int)(blockIdx.z >> 3);
    const int Me = counts[e];
    const int m0 = blockIdx.y * 64;
    if (m0 >= Me) return;
    const int n0 = blockIdx.x * 64;
    const int off = offsets[e];
    const int k0base = kc * 512;

    __shared__ __align__(16) __bf16 As[64][44];   // 88B stride: 8B-aligned, CF b64 groups
    __shared__ __align__(16) __bf16 Bs[64][44];   // [n][k]
    __shared__ int toks[64];

    const int tid = threadIdx.x;
    if (tid < 64) {
        int m = m0 + tid;
        if (m >= Me) m = Me - 1;          // clamp: loads valid, stores guarded
        toks[tid] = slot_token[off + m];
    }
    __syncthreads();

    // staging: thread -> row (tid>>2), k-oct (tid&3)*8; one bf16x8 each for A,B
    const int sr  = tid >> 2;
    const int soct = (tid & 3) * 8;
    const __bf16* aptr;
    if (IS_FC1) {
        aptr = A + (size_t)toks[sr] * ASR + soct;
    } else {
        int m = m0 + sr;
        if (m >= Me) m = Me - 1;
        aptr = A + (size_t)(off + m) * ASR + k0base + soct;
    }
    const __bf16* bptr = Wt + (size_t)e * K * N + (size_t)(n0 + sr) * K + k0base + soct;

    const int lane = tid & 63;
    const int wave = tid >> 6;
    const int wm = (wave >> 1) * 32, wn = (wave & 1) * 32;
    const int l15 = lane & 15, q = lane >> 4;

    f32x4 acc[2][2] = {};

    bf16x8 av = *(const bf16x8*)aptr;
    bf16x8 bv = *(const bf16x8*)bptr;

    for (int ks = 0; ks < 16; ++ks) {     // 16 * 32 = 512 K per chunk
        *(bf16x8*)&As[sr][soct] = av;
        *(bf16x8*)&Bs[sr][soct] = bv;
        __syncthreads();
        if (ks < 15) {                    // prefetch next K-step
            av = *(const bf16x8*)(aptr + (ks + 1) * 32);
            bv = *(const bf16x8*)(bptr + (ks + 1) * 32);
        }
        bf16x8 af0 = *(bf16x8*)&As[wm + l15][q * 8];
        bf16x8 af1 = *(bf16x8*)&As[wm + 16 + l15][q * 8];
        bf16x8 bf0 = *(bf16x8*)&Bs[wn + l15][q * 8];
        bf16x8 bf1 = *(bf16x8*)&Bs[wn + 16 + l15][q * 8];
        acc[0][0] = MFMA16(af0, bf0, acc[0][0], 0, 0, 0);
        acc[0][1] = MFMA16(af0, bf1, acc[0][1], 0, 0, 0);
        acc[1][0] = MFMA16(af1, bf0, acc[1][0], 0, 0, 0);
        acc[1][1] = MFMA16(af1, bf1, acc[1][1], 0, 0, 0);
        __syncthreads();
    }

    // Epilogue. C/D layout (verified m89): col = lane&15, row = (lane>>4)*4 + reg.
#pragma unroll
    for (int j = 0; j < 2; ++j) {
        const int gn = n0 + wn + j * 16 + l15;
        if (IS_FC1) {
            __bf16* hb = (__bf16*)out_;
            const float bv2 = bias[e * H_DIM + gn];
#pragma unroll
            for (int i = 0; i < 2; ++i)
#pragma unroll
                for (int r = 0; r < 4; ++r) {
                    int mrel = wm + i * 16 + q * 4 + r;
                    int m = m0 + mrel;
                    if (m < Me) {
                        float v = acc[i][j][r] + bv2;
                        hb[(size_t)(off + m) * H_DIM + gn] = (__bf16)fmaxf(v, 0.f);
                    }
                }
        } else {
            float* out = (float*)out_;
            const float bv2 = (kc == 0) ? bias[e * O_DIM + gn] : 0.f;
#pragma unroll
            for (int i = 0; i < 2; ++i)
#pragma unroll
                for (int r = 0; r < 4; ++r) {
                    int mrel = wm + i * 16 + q * 4 + r;
                    int m = m0 + mrel;
                    if (m < Me) {
                        int slot = off + m;
                        float w = slot_wt[slot];
                        int tok = toks[mrel];
                        atomicAdd(&out[(size_t)tok * O_DIM + gn],
                                  w * (acc[i][j][r] + bv2));
                    }
                }
        }
    }
}

extern "C" void kernel_launch(void* const* d_in, const int* in_sizes, int n_in,
                              void* d_out, int out_size, void* d_ws, size_t ws_size,
                              hipStream_t stream)
{
    const float* x  = (const float*)d_in[0];
    const float* Wg = (const float*)d_in[1];
    const float* bg = (const float*)d_in[2];
    const float* W1 = (const float*)d_in[3];
    const float* b1 = (const float*)d_in[4];
    const float* W2 = (const float*)d_in[5];
    const float* b2 = (const float*)d_in[6];
    float* out = (float*)d_out;
    char* ws = (char*)d_ws;

    int*    counts   = (int*)(ws + WS_COUNTS);
    int*    offsets  = (int*)(ws + WS_OFFSETS);
    int*    tok_e    = (int*)(ws + WS_TOK_E);
    float*  tok_w    = (float*)(ws + WS_TOK_W);
    int*    slot_tok = (int*)(ws + WS_SLOT_TOK);
    float*  slot_wt  = (float*)(ws + WS_SLOT_WT);
    __bf16* xb       = (__bf16*)(ws + WS_XB);
    __bf16* hb       = (__bf16*)(ws + WS_HB);
    __bf16* W1t      = (__bf16*)(ws + WS_W1T);
    __bf16* W2t      = (__bf16*)(ws + WS_W2T);

    prep_kernel<<<512, 256, 0, stream>>>((const float4*)x, (float4*)out, xb, counts);
    wconv_kernel<<<16384, 256, 0, stream>>>(W1, W2, W1t, W2t);
    gating_kernel<<<B_TOK / 4, 256, 0, stream>>>(x, Wg, bg, counts, tok_e, tok_w);
    scatter_kernel<<<1, B_TOK, 0, stream>>>(counts, tok_e, tok_w, offsets,
                                            slot_tok, slot_wt);
    moe_gemm<true><<<dim3(H_DIM / 64, 32, E_NUM), 256, 0, stream>>>(
        xb, W1t, b1, counts, offsets, slot_tok, slot_wt, hb);
    moe_gemm<false><<<dim3(O_DIM / 64, 32, E_NUM * 4), 256, 0, stream>>>(
        hb, W2t, b2, counts, offsets, slot_tok, slot_wt, out);
}

// Round 4
// 195.359 us; speedup vs baseline: 2.1731x; 1.0165x over previous
//
#include <hip/hip_runtime.h>
#include <math.h>

// MoE top-2-of-8: B=1024, I=512, H=2048, O=512, E=8, K=2.
// R4: m97-style GEMMs: global_load_lds(16B) staging into unpadded LDS tiles
// with XOR-chunk swizzle (bank-minimal ds_read_b128), BK=32 2-barrier K-loop.
// fc1: 64x128 tile (512 working blocks); fc2: 64x64, split-K=2 (512 blocks).
// Prologue fuses out-zero + x->bf16 + W1/W2 transpose->bf16 into one kernel.

#define B_TOK 1024
#define I_DIM 512
#define H_DIM 2048
#define O_DIM 512
#define E_NUM 8

#define WS_COUNTS   0                    // 8 ints
#define WS_OFFSETS  32                   // 8 ints
#define WS_TOK_E    64                   // [1024][2] int
#define WS_TOK_W    8256                 // [1024][2] float
#define WS_SLOT_TOK 16448                // [2048] int
#define WS_SLOT_WT  24640                // [2048] float
#define WS_XB       65536                // [1024][512] bf16 = 1 MB
#define WS_HB       (WS_XB + 1048576)    // [2048][2048] bf16 = 8 MB
#define WS_W1T      (WS_HB + 8388608)    // [8][2048][512] bf16 = 16 MB ([n][k])
#define WS_W2T      (WS_W1T + 16777216)  // [8][512][2048] bf16 = 16 MB ([n][k])

typedef __attribute__((ext_vector_type(8))) __bf16 bf16x8;
typedef __attribute__((ext_vector_type(4))) __bf16 bf16x4;
typedef __attribute__((ext_vector_type(4))) float f32x4;

#define MFMA16 __builtin_amdgcn_mfma_f32_16x16x32_bf16

// async global->LDS, 16B/lane; LDS dest is wave-uniform base + lane*16 (m104)
#define GL_LDS16(gp, lp)                                                      \
    __builtin_amdgcn_global_load_lds(                                         \
        (const __attribute__((address_space(1))) unsigned int*)(gp),          \
        (__attribute__((address_space(3))) unsigned int*)(lp), 16, 0, 0)

// ---------------------------------------------------------------------------
// Prologue: blocks [0,8192) transpose W1, [8192,16384) transpose W2,
// [16384,16896) zero out + convert x + zero counts.
__global__ __launch_bounds__(256) void prologue_kernel(
    const float* __restrict__ W1, const float* __restrict__ W2,
    const float4* __restrict__ x4,
    __bf16* __restrict__ W1t, __bf16* __restrict__ W2t,
    __bf16* __restrict__ xb, float4* __restrict__ out4, int* __restrict__ cnt)
{
    __shared__ __bf16 T[32][36];
    int id = blockIdx.x;
    const int tid = threadIdx.x;
    if (id >= 16384) {
        const int idx = (id - 16384) * 256 + tid;    // 131072 float4s
        out4[idx] = float4{0.f, 0.f, 0.f, 0.f};
        float4 v = x4[idx];
        bf16x4 o;
        o[0] = (__bf16)v.x; o[1] = (__bf16)v.y;
        o[2] = (__bf16)v.z; o[3] = (__bf16)v.w;
        *(bf16x4*)(xb + (size_t)idx * 4) = o;
        if (id == 16384 && tid < 16) cnt[tid] = 0;
        return;
    }
    const float* W;
    __bf16* Wt;
    int R, C;
    if (id < 8192) { W = W1; Wt = W1t; R = I_DIM; C = H_DIM; }
    else { id -= 8192; W = W2; Wt = W2t; R = H_DIM; C = O_DIM; }
    const int e = id >> 10;              // 1024 tiles (32x32) per expert
    const int t = id & 1023;
    const int tpr = C >> 5;
    const int r0 = (t / tpr) * 32;
    const int c0 = (t % tpr) * 32;
    W  += (size_t)e * R * C;
    Wt += (size_t)e * R * C;
    const int row = tid >> 3;            // 0..31
    const int c4  = (tid & 7) * 4;       // 0..28
    float4 v = *(const float4*)(W + (size_t)(r0 + row) * C + c0 + c4);
    T[c4 + 0][row] = (__bf16)v.x;
    T[c4 + 1][row] = (__bf16)v.y;
    T[c4 + 2][row] = (__bf16)v.z;
    T[c4 + 3][row] = (__bf16)v.w;
    __syncthreads();
    bf16x4 o;
    o[0] = T[row][c4 + 0];
    o[1] = T[row][c4 + 1];
    o[2] = T[row][c4 + 2];
    o[3] = T[row][c4 + 3];
    *(bf16x4*)(Wt + (size_t)(c0 + row) * R + r0 + c4) = o;
}

// One wave per token: logits = x @ Wg + bg, top-2, renormalized softmax weights.
__global__ __launch_bounds__(256) void gating_kernel(
    const float* __restrict__ x, const float* __restrict__ Wg,
    const float* __restrict__ bg,
    int* __restrict__ counts, int* __restrict__ tok_e, float* __restrict__ tok_w)
{
    const int lane = threadIdx.x & 63;
    const int t = blockIdx.x * 4 + (threadIdx.x >> 6);
    const float* xr = x + (size_t)t * I_DIM;
    float acc[8];
#pragma unroll
    for (int e = 0; e < 8; ++e) acc[e] = 0.f;
    for (int i = lane; i < I_DIM; i += 64) {
        float xv = xr[i];
        const float4* wr = (const float4*)(Wg + (size_t)i * 8);
        float4 wa = wr[0], wb = wr[1];
        acc[0] = fmaf(xv, wa.x, acc[0]);
        acc[1] = fmaf(xv, wa.y, acc[1]);
        acc[2] = fmaf(xv, wa.z, acc[2]);
        acc[3] = fmaf(xv, wa.w, acc[3]);
        acc[4] = fmaf(xv, wb.x, acc[4]);
        acc[5] = fmaf(xv, wb.y, acc[5]);
        acc[6] = fmaf(xv, wb.z, acc[6]);
        acc[7] = fmaf(xv, wb.w, acc[7]);
    }
#pragma unroll
    for (int off = 32; off > 0; off >>= 1)
#pragma unroll
        for (int e = 0; e < 8; ++e)
            acc[e] += __shfl_xor(acc[e], off, 64);
    if (lane == 0) {
        float l[8];
#pragma unroll
        for (int e = 0; e < 8; ++e) l[e] = acc[e] + bg[e];
        int e0 = 0;
        for (int e = 1; e < 8; ++e) if (l[e] > l[e0]) e0 = e;
        int e1 = (e0 == 0) ? 1 : 0;
        for (int e = 0; e < 8; ++e) {
            if (e == e0) continue;
            if (l[e] > l[e1]) e1 = e;
        }
        float w0 = 1.f / (1.f + expf(l[e1] - l[e0]));  // p0/(p0+p1)
        tok_e[t * 2]     = e0;
        tok_e[t * 2 + 1] = e1;
        tok_w[t * 2]     = w0;
        tok_w[t * 2 + 1] = 1.f - w0;
        atomicAdd(&counts[e0], 1);
        atomicAdd(&counts[e1], 1);
    }
}

// Single block: prefix over 8 counts, scatter into compact per-expert slot lists.
__global__ __launch_bounds__(1024) void scatter_kernel(
    const int* __restrict__ counts, const int* __restrict__ tok_e,
    const float* __restrict__ tok_w,
    int* __restrict__ offsets, int* __restrict__ slot_token,
    float* __restrict__ slot_wt)
{
    __shared__ int soff[8];
    __shared__ int scur[8];
    const int tid = threadIdx.x;
    if (tid == 0) {
        int run = 0;
        for (int e = 0; e < 8; ++e) { soff[e] = run; run += counts[e]; }
    }
    if (tid < 8) scur[tid] = 0;
    __syncthreads();
    if (tid < 8) offsets[tid] = soff[tid];
#pragma unroll
    for (int k = 0; k < 2; ++k) {
        int e = tok_e[tid * 2 + k];
        int pos = atomicAdd(&scur[e], 1);
        int slot = soff[e] + pos;
        slot_token[slot] = tid;
        slot_wt[slot] = tok_w[tid * 2 + k];
    }
}

// ---------------------------------------------------------------------------
// m97-style MFMA GEMM.  BM=64, BK=32, 256 threads (4 waves, 2x2).
// LDS tiles unpadded [rows][32] bf16; element (r, kchunk c) at phys chunk
// c ^ ((r>>1)&3)  -> ds_read_b128 hits the 2-access/bank minimum (free, m136).
// IS_FC1:  A=xb gathered via slot_token, B=W1t[e] [n][k], BN=128, Out=hb (relu+bias)
// !IS_FC1: A=hb direct, B=W2t[e] [n][k], BN=64, split-K=2, Out=out f32 atomic
template <bool IS_FC1>
__global__ __launch_bounds__(256) void moe_gemm(
    const __bf16* __restrict__ A, const __bf16* __restrict__ Wt,
    const float* __restrict__ bias,
    const int* __restrict__ counts, const int* __restrict__ offsets,
    const int* __restrict__ slot_token, const float* __restrict__ slot_wt,
    void* __restrict__ out_)
{
    constexpr int N     = IS_FC1 ? H_DIM : O_DIM;
    constexpr int K     = IS_FC1 ? I_DIM : H_DIM;     // also A row stride
    constexpr int BN    = IS_FC1 ? 128 : 64;
    constexpr int ITERS = IS_FC1 ? 16 : 32;           // BK=32; fc2 chunk=1024
    constexpr int NB    = IS_FC1 ? 4 : 2;             // b-frags per wave

    const int e  = IS_FC1 ? blockIdx.z : (blockIdx.z & 7);
    const int kc = IS_FC1 ? 0 : (int)(blockIdx.z >> 3);
    const int Me = counts[e];
    const int m0 = blockIdx.y * 64;
    if (m0 >= Me) return;
    const int n0 = blockIdx.x * BN;
    const int off = offsets[e];
    const int k0 = kc * 1024;

    __shared__ __align__(16) __bf16 As[64 * 32];      // 4 KB
    __shared__ __align__(16) __bf16 Bs[BN * 32];      // 8 / 4 KB
    __shared__ int toks[64];

    const int tid = threadIdx.x;
    const int lane = tid & 63, w = tid >> 6;
    if (tid < 64) {
        int m = m0 + tid;
        if (m >= Me) m = Me - 1;          // clamp: loads valid, stores guarded
        toks[tid] = slot_token[off + m];
    }
    __syncthreads();

    // ---- staging setup: per-lane global ptrs, wave-uniform LDS bases ----
    const int srow = lane >> 2;                        // row within 16-row inst
    const int ar = w * 16 + srow;
    const int ac = (lane & 3) ^ ((ar >> 1) & 3);       // memory k-chunk
    const __bf16* a_g;
    if (IS_FC1) {
        a_g = A + (size_t)toks[ar] * K + ac * 8;
    } else {
        int m = m0 + ar;
        if (m >= Me) m = Me - 1;
        a_g = A + (size_t)(off + m) * K + k0 + ac * 8;
    }
    const __bf16* Wte = Wt + (size_t)e * N * K;
    const int br0 = w * (IS_FC1 ? 32 : 16) + srow;
    const __bf16* b_g0 = Wte + (size_t)(n0 + br0) * K + k0
                         + (((lane & 3) ^ ((br0 >> 1) & 3)) * 8);
    const __bf16* b_g1 = nullptr;
    if (IS_FC1) {
        const int br1 = br0 + 16;
        b_g1 = Wte + (size_t)(n0 + br1) * K + k0
               + (((lane & 3) ^ ((br1 >> 1) & 3)) * 8);
    }
    __bf16* as_base  = &As[w * 16 * 32];
    __bf16* bs_base0 = &Bs[w * (IS_FC1 ? 32 : 16) * 32];
    __bf16* bs_base1 = IS_FC1 ? &Bs[(w * 32 + 16) * 32] : nullptr;

    // ---- fragment read offsets (swizzled) ----
    const int l15 = lane & 15, q = lane >> 4;
    const int wm = (w >> 1) * 32;
    const int wn = (w & 1) * (IS_FC1 ? 64 : 32);
    int aoff[2], boff[NB];
#pragma unroll
    for (int i = 0; i < 2; ++i) {
        int m = wm + i * 16 + l15;
        aoff[i] = m * 32 + (q ^ ((m >> 1) & 3)) * 8;
    }
#pragma unroll
    for (int j = 0; j < NB; ++j) {
        int n = wn + j * 16 + l15;
        boff[j] = n * 32 + (q ^ ((n >> 1) & 3)) * 8;
    }

    f32x4 acc[2][NB] = {};

    for (int ks = 0; ks < ITERS; ++ks) {
        GL_LDS16(a_g, as_base);
        GL_LDS16(b_g0, bs_base0);
        if (IS_FC1) GL_LDS16(b_g1, bs_base1);
        a_g += 32; b_g0 += 32;
        if (IS_FC1) b_g1 += 32;
        __syncthreads();                  // drains vmcnt: tiles resident
        bf16x8 af[2], bfr[NB];
#pragma unroll
        for (int i = 0; i < 2; ++i) af[i] = *(const bf16x8*)&As[aoff[i]];
#pragma unroll
        for (int j = 0; j < NB; ++j) bfr[j] = *(const bf16x8*)&Bs[boff[j]];
#pragma unroll
        for (int i = 0; i < 2; ++i)
#pragma unroll
            for (int j = 0; j < NB; ++j)
                acc[i][j] = MFMA16(af[i], bfr[j], acc[i][j], 0, 0, 0);
        __syncthreads();                  // protect tiles from next staging
    }

    // Epilogue. C/D layout (verified m89): col = lane&15, row = (lane>>4)*4 + reg.
#pragma unroll
    for (int j = 0; j < NB; ++j) {
        const int gn = n0 + wn + j * 16 + l15;
        if (IS_FC1) {
            __bf16* hb = (__bf16*)out_;
            const float bv = bias[e * H_DIM + gn];
#pragma unroll
            for (int i = 0; i < 2; ++i)
#pragma unroll
                for (int r = 0; r < 4; ++r) {
                    int m = m0 + wm + i * 16 + q * 4 + r;
                    if (m < Me) {
                        float v = acc[i][j][r] + bv;
                        hb[(size_t)(off + m) * H_DIM + gn] = (__bf16)fmaxf(v, 0.f);
                    }
                }
        } else {
            float* out = (float*)out_;
            const float bv = (kc == 0) ? bias[e * O_DIM + gn] : 0.f;
#pragma unroll
            for (int i = 0; i < 2; ++i)
#pragma unroll
                for (int r = 0; r < 4; ++r) {
                    int mrel = wm + i * 16 + q * 4 + r;
                    int m = m0 + mrel;
                    if (m < Me) {
                        int slot = off + m;
                        atomicAdd(&out[(size_t)toks[mrel] * O_DIM + gn],
                                  slot_wt[slot] * (acc[i][j][r] + bv));
                    }
                }
        }
    }
}

extern "C" void kernel_launch(void* const* d_in, const int* in_sizes, int n_in,
                              void* d_out, int out_size, void* d_ws, size_t ws_size,
                              hipStream_t stream)
{
    const float* x  = (const float*)d_in[0];
    const float* Wg = (const float*)d_in[1];
    const float* bg = (const float*)d_in[2];
    const float* W1 = (const float*)d_in[3];
    const float* b1 = (const float*)d_in[4];
    const float* W2 = (const float*)d_in[5];
    const float* b2 = (const float*)d_in[6];
    float* out = (float*)d_out;
    char* ws = (char*)d_ws;

    int*    counts   = (int*)(ws + WS_COUNTS);
    int*    offsets  = (int*)(ws + WS_OFFSETS);
    int*    tok_e    = (int*)(ws + WS_TOK_E);
    float*  tok_w    = (float*)(ws + WS_TOK_W);
    int*    slot_tok = (int*)(ws + WS_SLOT_TOK);
    float*  slot_wt  = (float*)(ws + WS_SLOT_WT);
    __bf16* xb       = (__bf16*)(ws + WS_XB);
    __bf16* hb       = (__bf16*)(ws + WS_HB);
    __bf16* W1t      = (__bf16*)(ws + WS_W1T);
    __bf16* W2t      = (__bf16*)(ws + WS_W2T);

    prologue_kernel<<<16896, 256, 0, stream>>>(W1, W2, (const float4*)x,
                                               W1t, W2t, xb, (float4*)out, counts);
    gating_kernel<<<B_TOK / 4, 256, 0, stream>>>(x, Wg, bg, counts, tok_e, tok_w);
    scatter_kernel<<<1, B_TOK, 0, stream>>>(counts, tok_e, tok_w, offsets,
                                            slot_tok, slot_wt);
    // fc1: 16 n-tiles x up-to-32 m-tiles x 8 experts (~512 working blocks)
    moe_gemm<true><<<dim3(16, 32, 8), 256, 0, stream>>>(
        xb, W1t, b1, counts, offsets, slot_tok, slot_wt, hb);
    // fc2: 8 n-tiles x up-to-32 m-tiles x (8 experts * 2 split-K)
    moe_gemm<false><<<dim3(8, 32, 16), 256, 0, stream>>>(
        hb, W2t, b2, counts, offsets, slot_tok, slot_wt, out);
}